// Round 8
// baseline (286.676 us; speedup 1.0000x reference)
//
#include <hip/hip_runtime.h>
#include <stdint.h>
#include <math.h>

#define SEQ 2048
#define NH 16
#define DM 1024

typedef __bf16 bf16x8 __attribute__((ext_vector_type(8)));
typedef __bf16 bf16x2 __attribute__((ext_vector_type(2)));
typedef short s16x4 __attribute__((ext_vector_type(4)));
typedef float f32x4 __attribute__((ext_vector_type(4)));
typedef float f32x2 __attribute__((ext_vector_type(2)));

#define ASM_VMCNT0  asm volatile("s_waitcnt vmcnt(0)" ::: "memory")
#define ASM_BARRIER asm volatile("s_barrier" ::: "memory")

__device__ __forceinline__ unsigned short f2bf(float f) {
  union { float f; unsigned u; } v; v.f = f;
  unsigned r = v.u + 0x7fffu + ((v.u >> 16) & 1u);
  return (unsigned short)(r >> 16);
}
__device__ __forceinline__ unsigned pk2(float a, float b) {
  f32x2 v = {a, b};
  bf16x2 r = __builtin_convertvector(v, bf16x2);  // v_cvt_pk_bf16_f32
  union { bf16x2 h; unsigned u; } c; c.h = r;
  return c.u;
}
__device__ __forceinline__ void load_lds16(const void* g, void* l) {
  __builtin_amdgcn_global_load_lds((__attribute__((address_space(1))) void*)g,
                                   (__attribute__((address_space(3))) void*)l,
                                   16, 0, 0);
}

// ---------------------------------------------------------------------------
// fp32 -> bf16 conversion: x (4M) + wq/wk/wv/wo (1M each) into ws.
// ---------------------------------------------------------------------------
__global__ void cvt_all(const float* __restrict__ x, const float* __restrict__ wq,
                        const float* __restrict__ wk, const float* __restrict__ wv,
                        const float* __restrict__ wo, unsigned short* __restrict__ ws) {
  const int i = blockIdx.x * blockDim.x + threadIdx.x;
  const int off = i * 4;
  const float* src;
  unsigned short* dst;
  if (off < 4194304) {
    src = x + off;  dst = ws + off;
  } else {
    const int r = off - 4194304;
    const int w = r >> 20, o = r & 1048575;
    const float* tabs[4] = {wq, wk, wv, wo};
    src = tabs[w] + o;  dst = ws + 4194304 + (w << 20) + o;
  }
  const float4 v = *(const float4*)src;
  uint2 u;
  u.x = pk2(v.x, v.y);
  u.y = pk2(v.z, v.w);
  *(uint2*)dst = u;
}

// ---------------------------------------------------------------------------
// Fused QKV projection: C = x (4096x1024) @ W3^T (W3 = [wq;wk;wv], 3072x1024).
// 128x128 tiles, grid (24,32) = 768 blocks; 3 blocks/CU -> all co-resident.
// ---------------------------------------------------------------------------
__launch_bounds__(256, 3)
__global__ void gemm_qkv(const unsigned short* __restrict__ X,
                         const unsigned short* __restrict__ W3,
                         unsigned short* __restrict__ Qr,
                         unsigned short* __restrict__ Kr,
                         unsigned short* __restrict__ Vt,
                         const int* __restrict__ tp) {
  __shared__ __align__(16) char smem[32768];

  const int t = threadIdx.x;
  const int lane = t & 63, wave = t >> 6;
  const int quad = lane >> 4, l16 = lane & 15;
  const int m0 = blockIdx.y * 128, n0 = blockIdx.x * 128;
  const int wm = (wave >> 1) * 64, wn = (wave & 1) * 64;

  f32x4 acc[4][4];
#pragma unroll
  for (int i = 0; i < 4; i++)
#pragma unroll
    for (int j = 0; j < 4; j++) { acc[i][j][0]=0.f; acc[i][j][1]=0.f; acc[i][j][2]=0.f; acc[i][j][3]=0.f; }

  const int rr = t >> 2;
  const int cc = (t & 3) * 8;

#define QKV_STAGE(bufidx, k0_) do {                                               \
    char* a_ = smem + (bufidx) * 8192;                                            \
    char* b_ = smem + 16384 + (bufidx) * 8192;                                    \
    _Pragma("unroll")                                                             \
    for (int i_ = 0; i_ < 2; i_++) {                                              \
      load_lds16(X  + (uint64_t)(m0 + i_ * 64 + rr) * 1024 + (k0_) + cc,          \
                 a_ + i_ * 4096 + wave * 1024);                                   \
      load_lds16(W3 + (uint64_t)(n0 + i_ * 64 + rr) * 1024 + (k0_) + cc,          \
                 b_ + i_ * 4096 + wave * 1024);                                   \
    }                                                                             \
  } while (0)

  QKV_STAGE(0, 0);

  for (int k0 = 0; k0 < 1024; k0 += 32) {
    const int buf = (k0 >> 5) & 1;
    ASM_VMCNT0;
    ASM_BARRIER;
    if (k0 + 32 < 1024) QKV_STAGE(buf ^ 1, k0 + 32);
    char* As = smem + buf * 8192;
    char* Bs = smem + 16384 + buf * 8192;

    bf16x8 af[4], bfr[4];
#pragma unroll
    for (int i = 0; i < 4; i++) {
      af[i]  = *(const bf16x8*)(As + (wm + i * 16 + l16) * 64 + quad * 16);
      bfr[i] = *(const bf16x8*)(Bs + (wn + i * 16 + l16) * 64 + quad * 16);
    }
#pragma unroll
    for (int i = 0; i < 4; i++)
#pragma unroll
      for (int j = 0; j < 4; j++)
        acc[i][j] = __builtin_amdgcn_mfma_f32_16x16x32_bf16(af[i], bfr[j], acc[i][j], 0, 0, 0);
  }
#undef QKV_STAGE

  if (n0 < 2048) {
    unsigned short* dst = (n0 < 1024) ? Qr : Kr;
    float fr[4]; int dd[4], hh[4];
#pragma unroll
    for (int j = 0; j < 4; j++) {
      const int n = n0 + wn + j * 16 + l16;
      dd[j] = n & 63;
      hh[j] = (n & 1023) >> 6;
      fr[j] = __builtin_amdgcn_exp2f(-0.20762050594f * (float)(dd[j] & ~1)) * 0.15915494309f;
    }
    const float sgnodd = (l16 & 1) ? 1.f : -1.f;
#pragma unroll
    for (int i = 0; i < 4; i++) {
#pragma unroll
      for (int r = 0; r < 4; r++) {
        const int m = m0 + wm + i * 16 + quad * 4 + r;
        const int s = m & 2047, b = m >> 11;
        const float posf = (float)tp[m];
#pragma unroll
        for (int j = 0; j < 4; j++) {
          const float v = acc[i][j][r];
          const float p = __shfl_xor(v, 1);
          float rev = posf * fr[j];
          rev -= floorf(rev);
          float sn, cs;
          asm("v_sin_f32 %0, %1" : "=v"(sn) : "v"(rev));
          asm("v_cos_f32 %0, %1" : "=v"(cs) : "v"(rev));
          const float rv = fmaf(v, cs, p * sn * sgnodd);
          dst[((uint64_t)((b * NH + hh[j]) * SEQ + s)) * 64 + dd[j]] = f2bf(rv);
        }
      }
    }
  } else {
#pragma unroll
    for (int i = 0; i < 4; i++) {
      const int m = m0 + wm + i * 16 + quad * 4;
      const int s = m & 2047, b = m >> 11;
#pragma unroll
      for (int j = 0; j < 4; j++) {
        const int n = n0 - 2048 + wn + j * 16 + l16;
        const int h = n >> 6, d = n & 63;
        uint2 w;
        w.x = pk2(acc[i][j][0], acc[i][j][1]);
        w.y = pk2(acc[i][j][2], acc[i][j][3]);
        *(uint2*)(Vt + ((uint64_t)((b * NH + h) * 64 + d)) * SEQ + s) = w;
      }
    }
  }
}

// ---------------------------------------------------------------------------
// Output projection: C = At (4096x1024) @ wo^T, fp32 out. 128x64 tiles.
// ---------------------------------------------------------------------------
__launch_bounds__(256, 2)
__global__ void gemm_ao(const unsigned short* __restrict__ A,
                        const unsigned short* __restrict__ B,
                        float* __restrict__ C) {
  __shared__ __align__(16) char smem[24576];

  const int t = threadIdx.x;
  const int lane = t & 63, wave = t >> 6;
  const int quad = lane >> 4, l16 = lane & 15;
  const int m0 = blockIdx.y * 128, n0 = blockIdx.x * 64;
  const int wm = (wave >> 1) * 64, wn = (wave & 1) * 32;

  f32x4 acc[4][2];
#pragma unroll
  for (int i = 0; i < 4; i++)
#pragma unroll
    for (int j = 0; j < 2; j++) { acc[i][j][0]=0.f; acc[i][j][1]=0.f; acc[i][j][2]=0.f; acc[i][j][3]=0.f; }

  const int rr = t >> 2;
  const int cc = (t & 3) * 8;

#define AO_STAGE(bufidx, k0_) do {                                                \
    char* a_ = smem + (bufidx) * 8192;                                            \
    char* b_ = smem + 16384 + (bufidx) * 4096;                                    \
    _Pragma("unroll")                                                             \
    for (int i_ = 0; i_ < 2; i_++)                                                \
      load_lds16(A + (uint64_t)(m0 + i_ * 64 + rr) * 1024 + (k0_) + cc,           \
                 a_ + i_ * 4096 + wave * 1024);                                   \
    load_lds16(B + (uint64_t)(n0 + rr) * 1024 + (k0_) + cc, b_ + wave * 1024);    \
  } while (0)

  AO_STAGE(0, 0);

  for (int k0 = 0; k0 < 1024; k0 += 32) {
    const int buf = (k0 >> 5) & 1;
    ASM_VMCNT0;
    ASM_BARRIER;
    if (k0 + 32 < 1024) AO_STAGE(buf ^ 1, k0 + 32);
    char* As = smem + buf * 8192;
    char* Bs = smem + 16384 + buf * 4096;

    bf16x8 af[4], bfr[2];
#pragma unroll
    for (int i = 0; i < 4; i++)
      af[i] = *(const bf16x8*)(As + (wm + i * 16 + l16) * 64 + quad * 16);
#pragma unroll
    for (int j = 0; j < 2; j++)
      bfr[j] = *(const bf16x8*)(Bs + (wn + j * 16 + l16) * 64 + quad * 16);
#pragma unroll
    for (int i = 0; i < 4; i++)
#pragma unroll
      for (int j = 0; j < 2; j++)
        acc[i][j] = __builtin_amdgcn_mfma_f32_16x16x32_bf16(af[i], bfr[j], acc[i][j], 0, 0, 0);
  }
#undef AO_STAGE

#pragma unroll
  for (int i = 0; i < 4; i++)
#pragma unroll
    for (int j = 0; j < 2; j++)
#pragma unroll
      for (int r = 0; r < 4; r++) {
        const int m = m0 + wm + i * 16 + quad * 4 + r;
        const int n = n0 + wn + j * 16 + l16;
        C[(uint64_t)m * DM + n] = acc[i][j][r];
      }
}

// ---------------------------------------------------------------------------
// Flash attention: 256 blocks x 512 threads (8 waves). Block = one bh plane,
// Q-tile pair (128-row tiles a and 15-a) -> exactly 34 key-tile iterations
// per block (uniform, 1 block/CU, zero tail).
// PV uses v_mfma_f32_16x16x16_bf16: its B-layout (k=quad*4+j, n=l16) equals
// the S^T C-layout (key=quad*4+r, q=l16), so P stays in REGISTERS -- no LDS
// round-trip. LDS/iter/wave: 8 b128 K-frags + 16 b64 V-frags only.
// ---------------------------------------------------------------------------
__launch_bounds__(512, 2)
__global__ void flash_attn(const unsigned short* __restrict__ Q,
                           const unsigned short* __restrict__ K,
                           const unsigned short* __restrict__ Vt,
                           unsigned short* __restrict__ Oa) {
  __shared__ __align__(16) char smem[32768];
  // K dbuf: 0 / 8192; V dbuf: 16384 / 24576

  const int t = threadIdx.x;
  const int lane = t & 63, wave = t >> 6;    // wave = 0..7
  const int quad = lane >> 4, l16 = lane & 15;
  const int lid = blockIdx.x;
  const int bh = lid & 31;
  const int a = lid >> 5;                    // 0..7 -> tile pair (a, 15-a)
  const uint64_t base = (uint64_t)bh * (SEQ * 64);
  const int qb0 = a * 128, qb1 = (15 - a) * 128;
  const int n0 = 2 * a + 2;                  // phase-0 iters (total 34)
  const int qg0 = qb0 + wave * 16 + l16;
  const int qg1 = qb1 + wave * 16 + l16;
  const int b = bh >> 4, h = bh & 15;

  // Q B-fragments for both phases (n=q=l16, k=d=kk*32+quad*8+j)
  bf16x8 qf0[2], qf1[2];
  {
    const unsigned short* qp = Q + base + (uint64_t)qg0 * 64 + quad * 8;
    qf0[0] = *(const bf16x8*)qp;  qf0[1] = *(const bf16x8*)(qp + 32);
    const unsigned short* qq = Q + base + (uint64_t)qg1 * 64 + quad * 8;
    qf1[0] = *(const bf16x8*)qq;  qf1[1] = *(const bf16x8*)(qq + 32);
  }

  f32x4 o[4];
#pragma unroll
  for (int i = 0; i < 4; i++) { o[i][0]=0.f; o[i][1]=0.f; o[i][2]=0.f; o[i][3]=0.f; }
  float lI = 0.f;

  // staging: 512 threads cover a full 64-row tile in one call.
  const int srow = wave * 8 + (lane >> 3);
  const int sc = ((lane & 7) ^ ((lane >> 3) & 7)) * 8;   // shorts
  const int swz = (l16 & 7);

#define STAGE(bufidx, kb_) do {                                                   \
    load_lds16(K  + base + (uint64_t)((kb_) + srow) * 64 + sc,                    \
               smem + (bufidx) * 8192 + wave * 1024);                             \
    load_lds16(Vt + base + (uint64_t)srow * SEQ + (kb_) + sc,                     \
               smem + 16384 + (bufidx) * 8192 + wave * 1024);                     \
  } while (0)

  STAGE(0, 0);

  const float c1 = 0.18033688011f;  // log2(e)/8

  for (int it = 0; it < 34; it++) {
    const bool ph1 = it >= n0;
    const int kb = (ph1 ? it - n0 : it) * 64;
    const int buf = it & 1;
    ASM_VMCNT0;     // my stage(it) loads done (issued a full iteration ago)
    ASM_BARRIER;
    if (it + 1 < 34) {
      const int itn = it + 1;
      const int kbn = ((itn >= n0) ? itn - n0 : itn) * 64;
      STAGE(buf ^ 1, kbn);
    }
    char* ks = smem + buf * 8192;
    char* vs = smem + 16384 + buf * 8192;

    const bf16x8* qf = ph1 ? qf1 : qf0;
    const int qg = ph1 ? qg1 : qg0;
    const int qb = ph1 ? qb1 : qb0;
    int nbmax = ((qb + wave * 16 + 15 - kb) >> 4) + 1;
    nbmax = nbmax > 4 ? 4 : (nbmax < 0 ? 0 : nbmax);
    const bool diag = (kb + 63) > (qb + wave * 16);   // wave-uniform

    // S^T = K Q^T : key = kb + nb*16 + quad*4 + r, q = l16
    f32x4 sf[4];
    float ls = 0.f;
#pragma unroll
    for (int nb = 0; nb < 4; nb++) {
      if (nb < nbmax) {
        f32x4 s; s[0]=0.f; s[1]=0.f; s[2]=0.f; s[3]=0.f;
#pragma unroll
        for (int kk = 0; kk < 2; kk++) {
          bf16x8 kfr = *(const bf16x8*)(ks + (nb * 16 + l16) * 128 + (((kk * 4 + quad) ^ swz) * 16));
          s = __builtin_amdgcn_mfma_f32_16x16x32_bf16(kfr, qf[kk], s, 0, 0, 0);
        }
        if (diag) {
#pragma unroll
          for (int r = 0; r < 4; r++) {
            const int key = kb + nb * 16 + quad * 4 + r;
            const float p = (key <= qg) ? __builtin_amdgcn_exp2f(s[r] * c1) : 0.f;
            sf[nb][r] = p;  ls += p;
          }
        } else {
#pragma unroll
          for (int r = 0; r < 4; r++) {
            const float p = __builtin_amdgcn_exp2f(s[r] * c1);
            sf[nb][r] = p;  ls += p;
          }
        }
      }
    }
    lI += ls;   // lane-local partial (this quad's keys); reduced per phase

    // P B-fragments in registers: pf[nb] = sf[nb][0..3] as bf16x4
    // (16x16x16 B-layout k=quad*4+j == S^T C-layout key=quad*4+r)
    s16x4 pf[4];
#pragma unroll
    for (int nb = 0; nb < 4; nb++) {
      if (nb < nbmax) {
        union { uint2 u; s16x4 h; } pc;
        pc.u.x = pk2(sf[nb][0], sf[nb][1]);
        pc.u.y = pk2(sf[nb][2], sf[nb][3]);
        pf[nb] = pc.h;
      }
    }

    // O^T += V^T P^T via K=16 MFMA: A=V-frag (m=d, k=quad*4+j), B=pf[nb]
    for (int nb = 0; nb < nbmax; nb++) {
#pragma unroll
      for (int db = 0; db < 4; db++) {
        s16x4 vf = *(const s16x4*)(vs + (db * 16 + l16) * 128 +
                                   (((2 * nb + (quad >> 1)) ^ swz) * 16) + (quad & 1) * 8);
        o[db] = __builtin_amdgcn_mfma_f32_16x16x16bf16_1k(vf, pf[nb], o[db], 0, 0, 0);
      }
    }

    if (it == n0 - 1) {
      // end of phase 0: reduce l across quads, normalize, store, reset
      float lr = lI;
      lr += __shfl_xor(lr, 16);
      lr += __shfl_xor(lr, 32);
      const float invl = 1.0f / lr;
      unsigned short* orow = Oa + ((uint64_t)(b * SEQ + qg0)) * DM + h * 64 + quad * 4;
#pragma unroll
      for (int db = 0; db < 4; db++) {
        uint2 w;
        w.x = pk2(o[db][0] * invl, o[db][1] * invl);
        w.y = pk2(o[db][2] * invl, o[db][3] * invl);
        *(uint2*)(orow + db * 16) = w;
        o[db][0]=0.f; o[db][1]=0.f; o[db][2]=0.f; o[db][3]=0.f;
      }
      lI = 0.f;
    }
  }
#undef STAGE

  // phase-1 epilogue
  float lr = lI;
  lr += __shfl_xor(lr, 16);
  lr += __shfl_xor(lr, 32);
  const float invl = 1.0f / lr;
  unsigned short* orow = Oa + ((uint64_t)(b * SEQ + qg1)) * DM + h * 64 + quad * 4;
#pragma unroll
  for (int db = 0; db < 4; db++) {
    uint2 w;
    w.x = pk2(o[db][0] * invl, o[db][1] * invl);
    w.y = pk2(o[db][2] * invl, o[db][3] * invl);
    *(uint2*)(orow + db * 16) = w;
  }
}

extern "C" void kernel_launch(void* const* d_in, const int* in_sizes, int n_in,
                              void* d_out, int out_size, void* d_ws, size_t ws_size,
                              hipStream_t stream) {
  const float* x  = (const float*)d_in[0];
  const int* tp   = (const int*)d_in[1];
  const float* wq = (const float*)d_in[2];
  const float* wk = (const float*)d_in[3];
  const float* wv = (const float*)d_in[4];
  const float* wo = (const float*)d_in[5];
  float* out = (float*)d_out;

  unsigned short* ws = (unsigned short*)d_ws;
  unsigned short* xb  = ws;                   // (b,s,dm) bf16        8 MB
  unsigned short* w3b = ws + 4194304;         // [wq;wk;wv] 3072x1024 6 MB
  unsigned short* wob = ws + 7340032;         // 2 MB
  unsigned short* Qr  = ws + 8388608;         // (b,h,s,64)  8 MB
  unsigned short* Kr  = ws + 12582912;        // (b,h,s,64)  8 MB
  unsigned short* Vt  = ws + 16777216;        // (b,h,64,s)  8 MB
  unsigned short* At  = ws + 20971520;        // (b,s,h*64)  8 MB

  cvt_all<<<8192, 256, 0, stream>>>(x, wq, wk, wv, wo, ws);
  gemm_qkv<<<dim3(24, 32), 256, 0, stream>>>(xb, w3b, Qr, Kr, Vt, tp);
  flash_attn<<<256, 512, 0, stream>>>(Qr, Kr, Vt, At);
  gemm_ao<<<dim3(16, 32), 256, 0, stream>>>(At, wob, out);
}

// Round 9
// 179.749 us; speedup vs baseline: 1.5949x; 1.5949x over previous
//
#include <hip/hip_runtime.h>
#include <stdint.h>
#include <math.h>

#define SEQ 2048
#define NH 16
#define DM 1024

typedef __bf16 bf16x8 __attribute__((ext_vector_type(8)));
typedef __bf16 bf16x2 __attribute__((ext_vector_type(2)));
typedef short s16x4 __attribute__((ext_vector_type(4)));
typedef float f32x4 __attribute__((ext_vector_type(4)));
typedef float f32x2 __attribute__((ext_vector_type(2)));

#define ASM_VMCNT0  asm volatile("s_waitcnt vmcnt(0)" ::: "memory")
#define ASM_BARRIER asm volatile("s_barrier" ::: "memory")

__device__ __forceinline__ unsigned short f2bf(float f) {
  union { float f; unsigned u; } v; v.f = f;
  unsigned r = v.u + 0x7fffu + ((v.u >> 16) & 1u);
  return (unsigned short)(r >> 16);
}
__device__ __forceinline__ unsigned pk2(float a, float b) {
  f32x2 v = {a, b};
  bf16x2 r = __builtin_convertvector(v, bf16x2);  // v_cvt_pk_bf16_f32
  union { bf16x2 h; unsigned u; } c; c.h = r;
  return c.u;
}
__device__ __forceinline__ void load_lds16(const void* g, void* l) {
  __builtin_amdgcn_global_load_lds((__attribute__((address_space(1))) void*)g,
                                   (__attribute__((address_space(3))) void*)l,
                                   16, 0, 0);
}

// ---------------------------------------------------------------------------
// fp32 -> bf16 conversion: x (4M) + wq/wk/wv/wo (1M each) into ws.
// ---------------------------------------------------------------------------
__global__ void cvt_all(const float* __restrict__ x, const float* __restrict__ wq,
                        const float* __restrict__ wk, const float* __restrict__ wv,
                        const float* __restrict__ wo, unsigned short* __restrict__ ws) {
  const int i = blockIdx.x * blockDim.x + threadIdx.x;
  const int off = i * 4;
  const float* src;
  unsigned short* dst;
  if (off < 4194304) {
    src = x + off;  dst = ws + off;
  } else {
    const int r = off - 4194304;
    const int w = r >> 20, o = r & 1048575;
    const float* tabs[4] = {wq, wk, wv, wo};
    src = tabs[w] + o;  dst = ws + 4194304 + (w << 20) + o;
  }
  const float4 v = *(const float4*)src;
  uint2 u;
  u.x = pk2(v.x, v.y);
  u.y = pk2(v.z, v.w);
  *(uint2*)dst = u;
}

// ---------------------------------------------------------------------------
// Fused QKV projection: C = x (4096x1024) @ W3^T (W3 = [wq;wk;wv], 3072x1024).
// 128x128 tiles, grid (24,32) = 768 blocks; 3 blocks/CU -> all co-resident.
// ---------------------------------------------------------------------------
__launch_bounds__(256, 3)
__global__ void gemm_qkv(const unsigned short* __restrict__ X,
                         const unsigned short* __restrict__ W3,
                         unsigned short* __restrict__ Qr,
                         unsigned short* __restrict__ Kr,
                         unsigned short* __restrict__ Vt,
                         const int* __restrict__ tp) {
  __shared__ __align__(16) char smem[32768];

  const int t = threadIdx.x;
  const int lane = t & 63, wave = t >> 6;
  const int quad = lane >> 4, l16 = lane & 15;
  const int m0 = blockIdx.y * 128, n0 = blockIdx.x * 128;
  const int wm = (wave >> 1) * 64, wn = (wave & 1) * 64;

  f32x4 acc[4][4];
#pragma unroll
  for (int i = 0; i < 4; i++)
#pragma unroll
    for (int j = 0; j < 4; j++) { acc[i][j][0]=0.f; acc[i][j][1]=0.f; acc[i][j][2]=0.f; acc[i][j][3]=0.f; }

  const int rr = t >> 2;
  const int cc = (t & 3) * 8;

#define QKV_STAGE(bufidx, k0_) do {                                               \
    char* a_ = smem + (bufidx) * 8192;                                            \
    char* b_ = smem + 16384 + (bufidx) * 8192;                                    \
    _Pragma("unroll")                                                             \
    for (int i_ = 0; i_ < 2; i_++) {                                              \
      load_lds16(X  + (uint64_t)(m0 + i_ * 64 + rr) * 1024 + (k0_) + cc,          \
                 a_ + i_ * 4096 + wave * 1024);                                   \
      load_lds16(W3 + (uint64_t)(n0 + i_ * 64 + rr) * 1024 + (k0_) + cc,          \
                 b_ + i_ * 4096 + wave * 1024);                                   \
    }                                                                             \
  } while (0)

  QKV_STAGE(0, 0);

  for (int k0 = 0; k0 < 1024; k0 += 32) {
    const int buf = (k0 >> 5) & 1;
    ASM_VMCNT0;
    ASM_BARRIER;
    if (k0 + 32 < 1024) QKV_STAGE(buf ^ 1, k0 + 32);
    char* As = smem + buf * 8192;
    char* Bs = smem + 16384 + buf * 8192;

    bf16x8 af[4], bfr[4];
#pragma unroll
    for (int i = 0; i < 4; i++) {
      af[i]  = *(const bf16x8*)(As + (wm + i * 16 + l16) * 64 + quad * 16);
      bfr[i] = *(const bf16x8*)(Bs + (wn + i * 16 + l16) * 64 + quad * 16);
    }
#pragma unroll
    for (int i = 0; i < 4; i++)
#pragma unroll
      for (int j = 0; j < 4; j++)
        acc[i][j] = __builtin_amdgcn_mfma_f32_16x16x32_bf16(af[i], bfr[j], acc[i][j], 0, 0, 0);
  }
#undef QKV_STAGE

  if (n0 < 2048) {
    unsigned short* dst = (n0 < 1024) ? Qr : Kr;
    float fr[4]; int dd[4], hh[4];
#pragma unroll
    for (int j = 0; j < 4; j++) {
      const int n = n0 + wn + j * 16 + l16;
      dd[j] = n & 63;
      hh[j] = (n & 1023) >> 6;
      fr[j] = __builtin_amdgcn_exp2f(-0.20762050594f * (float)(dd[j] & ~1)) * 0.15915494309f;
    }
    const float sgnodd = (l16 & 1) ? 1.f : -1.f;
#pragma unroll
    for (int i = 0; i < 4; i++) {
#pragma unroll
      for (int r = 0; r < 4; r++) {
        const int m = m0 + wm + i * 16 + quad * 4 + r;
        const int s = m & 2047, b = m >> 11;
        const float posf = (float)tp[m];
#pragma unroll
        for (int j = 0; j < 4; j++) {
          const float v = acc[i][j][r];
          const float p = __shfl_xor(v, 1);
          float rev = posf * fr[j];
          rev -= floorf(rev);
          float sn, cs;
          asm("v_sin_f32 %0, %1" : "=v"(sn) : "v"(rev));
          asm("v_cos_f32 %0, %1" : "=v"(cs) : "v"(rev));
          const float rv = fmaf(v, cs, p * sn * sgnodd);
          dst[((uint64_t)((b * NH + hh[j]) * SEQ + s)) * 64 + dd[j]] = f2bf(rv);
        }
      }
    }
  } else {
#pragma unroll
    for (int i = 0; i < 4; i++) {
      const int m = m0 + wm + i * 16 + quad * 4;
      const int s = m & 2047, b = m >> 11;
#pragma unroll
      for (int j = 0; j < 4; j++) {
        const int n = n0 - 2048 + wn + j * 16 + l16;
        const int h = n >> 6, d = n & 63;
        uint2 w;
        w.x = pk2(acc[i][j][0], acc[i][j][1]);
        w.y = pk2(acc[i][j][2], acc[i][j][3]);
        *(uint2*)(Vt + ((uint64_t)((b * NH + h) * 64 + d)) * SEQ + s) = w;
      }
    }
  }
}

// ---------------------------------------------------------------------------
// Output projection: C = At (4096x1024) @ wo^T, fp32 out. 128x64 tiles.
// ---------------------------------------------------------------------------
__launch_bounds__(256, 2)
__global__ void gemm_ao(const unsigned short* __restrict__ A,
                        const unsigned short* __restrict__ B,
                        float* __restrict__ C) {
  __shared__ __align__(16) char smem[24576];

  const int t = threadIdx.x;
  const int lane = t & 63, wave = t >> 6;
  const int quad = lane >> 4, l16 = lane & 15;
  const int m0 = blockIdx.y * 128, n0 = blockIdx.x * 64;
  const int wm = (wave >> 1) * 64, wn = (wave & 1) * 32;

  f32x4 acc[4][2];
#pragma unroll
  for (int i = 0; i < 4; i++)
#pragma unroll
    for (int j = 0; j < 2; j++) { acc[i][j][0]=0.f; acc[i][j][1]=0.f; acc[i][j][2]=0.f; acc[i][j][3]=0.f; }

  const int rr = t >> 2;
  const int cc = (t & 3) * 8;

#define AO_STAGE(bufidx, k0_) do {                                                \
    char* a_ = smem + (bufidx) * 8192;                                            \
    char* b_ = smem + 16384 + (bufidx) * 4096;                                    \
    _Pragma("unroll")                                                             \
    for (int i_ = 0; i_ < 2; i_++)                                                \
      load_lds16(A + (uint64_t)(m0 + i_ * 64 + rr) * 1024 + (k0_) + cc,           \
                 a_ + i_ * 4096 + wave * 1024);                                   \
    load_lds16(B + (uint64_t)(n0 + rr) * 1024 + (k0_) + cc, b_ + wave * 1024);    \
  } while (0)

  AO_STAGE(0, 0);

  for (int k0 = 0; k0 < 1024; k0 += 32) {
    const int buf = (k0 >> 5) & 1;
    ASM_VMCNT0;
    ASM_BARRIER;
    if (k0 + 32 < 1024) AO_STAGE(buf ^ 1, k0 + 32);
    char* As = smem + buf * 8192;
    char* Bs = smem + 16384 + buf * 4096;

    bf16x8 af[4], bfr[2];
#pragma unroll
    for (int i = 0; i < 4; i++)
      af[i] = *(const bf16x8*)(As + (wm + i * 16 + l16) * 64 + quad * 16);
#pragma unroll
    for (int j = 0; j < 2; j++)
      bfr[j] = *(const bf16x8*)(Bs + (wn + j * 16 + l16) * 64 + quad * 16);
#pragma unroll
    for (int i = 0; i < 4; i++)
#pragma unroll
      for (int j = 0; j < 2; j++)
        acc[i][j] = __builtin_amdgcn_mfma_f32_16x16x32_bf16(af[i], bfr[j], acc[i][j], 0, 0, 0);
  }
#undef AO_STAGE

#pragma unroll
  for (int i = 0; i < 4; i++)
#pragma unroll
    for (int j = 0; j < 2; j++)
#pragma unroll
      for (int r = 0; r < 4; r++) {
        const int m = m0 + wm + i * 16 + quad * 4 + r;
        const int n = n0 + wn + j * 16 + l16;
        C[(uint64_t)m * DM + n] = acc[i][j][r];
      }
}

// ---------------------------------------------------------------------------
// Flash attention: 256 blocks x 512 threads (8 waves). Block = one bh plane,
// Q-tile pair (128-row tiles a and 15-a) -> exactly 34 key-tile iterations
// per block (uniform, 1 block/CU, zero tail).
// PV via v_mfma_f32_16x16x16bf16_1k with P in REGISTERS (B-layout k=quad*4+j
// == S^T C-layout key=quad*4+r). ALL nb loops compile-time unrolled with
// nb<nbmax guards -- r8's runtime-bounded loop forced pf[] to scratch (3x).
// ---------------------------------------------------------------------------
__launch_bounds__(512, 2)
__global__ void flash_attn(const unsigned short* __restrict__ Q,
                           const unsigned short* __restrict__ K,
                           const unsigned short* __restrict__ Vt,
                           unsigned short* __restrict__ Oa) {
  __shared__ __align__(16) char smem[32768];
  // K dbuf: 0 / 8192; V dbuf: 16384 / 24576

  const int t = threadIdx.x;
  const int lane = t & 63, wave = t >> 6;    // wave = 0..7
  const int quad = lane >> 4, l16 = lane & 15;
  const int lid = blockIdx.x;
  const int bh = lid & 31;
  const int a = lid >> 5;                    // 0..7 -> tile pair (a, 15-a)
  const uint64_t base = (uint64_t)bh * (SEQ * 64);
  const int qb0 = a * 128, qb1 = (15 - a) * 128;
  const int n0 = 2 * a + 2;                  // phase-0 iters (total 34)
  const int qg0 = qb0 + wave * 16 + l16;
  const int qg1 = qb1 + wave * 16 + l16;
  const int b = bh >> 4, h = bh & 15;

  // Q B-fragments for both phases (n=q=l16, k=d=kk*32+quad*8+j)
  bf16x8 qf0[2], qf1[2];
  {
    const unsigned short* qp = Q + base + (uint64_t)qg0 * 64 + quad * 8;
    qf0[0] = *(const bf16x8*)qp;  qf0[1] = *(const bf16x8*)(qp + 32);
    const unsigned short* qq = Q + base + (uint64_t)qg1 * 64 + quad * 8;
    qf1[0] = *(const bf16x8*)qq;  qf1[1] = *(const bf16x8*)(qq + 32);
  }

  f32x4 o[4];
#pragma unroll
  for (int i = 0; i < 4; i++) { o[i][0]=0.f; o[i][1]=0.f; o[i][2]=0.f; o[i][3]=0.f; }
  float lI = 0.f;

  // staging: 512 threads cover a full 64-row tile in one call.
  const int srow = wave * 8 + (lane >> 3);
  const int sc = ((lane & 7) ^ ((lane >> 3) & 7)) * 8;   // shorts
  const int swz = (l16 & 7);

#define STAGE(bufidx, kb_) do {                                                   \
    load_lds16(K  + base + (uint64_t)((kb_) + srow) * 64 + sc,                    \
               smem + (bufidx) * 8192 + wave * 1024);                             \
    load_lds16(Vt + base + (uint64_t)srow * SEQ + (kb_) + sc,                     \
               smem + 16384 + (bufidx) * 8192 + wave * 1024);                     \
  } while (0)

  STAGE(0, 0);

  const float c1 = 0.18033688011f;  // log2(e)/8

  for (int it = 0; it < 34; it++) {
    const bool ph1 = it >= n0;
    const int kb = (ph1 ? it - n0 : it) * 64;
    const int buf = it & 1;
    ASM_VMCNT0;     // my stage(it) loads done (issued a full iteration ago)
    ASM_BARRIER;
    if (it + 1 < 34) {
      const int itn = it + 1;
      const int kbn = ((itn >= n0) ? itn - n0 : itn) * 64;
      STAGE(buf ^ 1, kbn);
    }
    char* ks = smem + buf * 8192;
    char* vs = smem + 16384 + buf * 8192;

    const bf16x8* qf = ph1 ? qf1 : qf0;
    const int qg = ph1 ? qg1 : qg0;
    const int qb = ph1 ? qb1 : qb0;
    int nbmax = ((qb + wave * 16 + 15 - kb) >> 4) + 1;
    nbmax = nbmax > 4 ? 4 : (nbmax < 0 ? 0 : nbmax);
    const bool diag = (kb + 63) > (qb + wave * 16);   // wave-uniform

    // S^T = K Q^T : key = kb + nb*16 + quad*4 + r, q = l16
    f32x4 sf[4];
    float ls = 0.f;
#pragma unroll
    for (int nb = 0; nb < 4; nb++) {
      if (nb < nbmax) {
        f32x4 s; s[0]=0.f; s[1]=0.f; s[2]=0.f; s[3]=0.f;
#pragma unroll
        for (int kk = 0; kk < 2; kk++) {
          bf16x8 kfr = *(const bf16x8*)(ks + (nb * 16 + l16) * 128 + (((kk * 4 + quad) ^ swz) * 16));
          s = __builtin_amdgcn_mfma_f32_16x16x32_bf16(kfr, qf[kk], s, 0, 0, 0);
        }
        if (diag) {
#pragma unroll
          for (int r = 0; r < 4; r++) {
            const int key = kb + nb * 16 + quad * 4 + r;
            const float p = (key <= qg) ? __builtin_amdgcn_exp2f(s[r] * c1) : 0.f;
            sf[nb][r] = p;  ls += p;
          }
        } else {
#pragma unroll
          for (int r = 0; r < 4; r++) {
            const float p = __builtin_amdgcn_exp2f(s[r] * c1);
            sf[nb][r] = p;  ls += p;
          }
        }
      }
    }
    lI += ls;   // lane-local partial (this quad's keys); reduced per phase

    // PV with P in registers -- fully unrolled, compile-time indices only.
    // pf = sf[nb] packed bf16x4 (16x16x16 B-layout k=quad*4+j).
    // A=V-frag: b64 at row d=db*16+l16, keys nb*16+quad*4..+3.
#pragma unroll
    for (int nb = 0; nb < 4; nb++) {
      if (nb < nbmax) {
        union { uint2 u; s16x4 h; } pc;
        pc.u.x = pk2(sf[nb][0], sf[nb][1]);
        pc.u.y = pk2(sf[nb][2], sf[nb][3]);
#pragma unroll
        for (int db = 0; db < 4; db++) {
          s16x4 vf = *(const s16x4*)(vs + (db * 16 + l16) * 128 +
                                     (((2 * nb + (quad >> 1)) ^ swz) * 16) + (quad & 1) * 8);
          o[db] = __builtin_amdgcn_mfma_f32_16x16x16bf16_1k(vf, pc.h, o[db], 0, 0, 0);
        }
      }
    }

    if (it == n0 - 1) {
      // end of phase 0: reduce l across quads, normalize, store, reset
      float lr = lI;
      lr += __shfl_xor(lr, 16);
      lr += __shfl_xor(lr, 32);
      const float invl = 1.0f / lr;
      unsigned short* orow = Oa + ((uint64_t)(b * SEQ + qg0)) * DM + h * 64 + quad * 4;
#pragma unroll
      for (int db = 0; db < 4; db++) {
        uint2 w;
        w.x = pk2(o[db][0] * invl, o[db][1] * invl);
        w.y = pk2(o[db][2] * invl, o[db][3] * invl);
        *(uint2*)(orow + db * 16) = w;
        o[db][0]=0.f; o[db][1]=0.f; o[db][2]=0.f; o[db][3]=0.f;
      }
      lI = 0.f;
    }
  }
#undef STAGE

  // phase-1 epilogue
  float lr = lI;
  lr += __shfl_xor(lr, 16);
  lr += __shfl_xor(lr, 32);
  const float invl = 1.0f / lr;
  unsigned short* orow = Oa + ((uint64_t)(b * SEQ + qg1)) * DM + h * 64 + quad * 4;
#pragma unroll
  for (int db = 0; db < 4; db++) {
    uint2 w;
    w.x = pk2(o[db][0] * invl, o[db][1] * invl);
    w.y = pk2(o[db][2] * invl, o[db][3] * invl);
    *(uint2*)(orow + db * 16) = w;
  }
}

extern "C" void kernel_launch(void* const* d_in, const int* in_sizes, int n_in,
                              void* d_out, int out_size, void* d_ws, size_t ws_size,
                              hipStream_t stream) {
  const float* x  = (const float*)d_in[0];
  const int* tp   = (const int*)d_in[1];
  const float* wq = (const float*)d_in[2];
  const float* wk = (const float*)d_in[3];
  const float* wv = (const float*)d_in[4];
  const float* wo = (const float*)d_in[5];
  float* out = (float*)d_out;

  unsigned short* ws = (unsigned short*)d_ws;
  unsigned short* xb  = ws;                   // (b,s,dm) bf16        8 MB
  unsigned short* w3b = ws + 4194304;         // [wq;wk;wv] 3072x1024 6 MB
  unsigned short* wob = ws + 7340032;         // 2 MB
  unsigned short* Qr  = ws + 8388608;         // (b,h,s,64)  8 MB
  unsigned short* Kr  = ws + 12582912;        // (b,h,s,64)  8 MB
  unsigned short* Vt  = ws + 16777216;        // (b,h,64,s)  8 MB
  unsigned short* At  = ws + 20971520;        // (b,s,h*64)  8 MB

  cvt_all<<<8192, 256, 0, stream>>>(x, wq, wk, wv, wo, ws);
  gemm_qkv<<<dim3(24, 32), 256, 0, stream>>>(xb, w3b, Qr, Kr, Vt, tp);
  flash_attn<<<256, 512, 0, stream>>>(Qr, Kr, Vt, At);
  gemm_ao<<<dim3(16, 32), 256, 0, stream>>>(At, wob, out);
}

// Round 10
// 179.348 us; speedup vs baseline: 1.5984x; 1.0022x over previous
//
#include <hip/hip_runtime.h>
#include <stdint.h>
#include <math.h>

#define SEQ 2048
#define NH 16
#define DM 1024

typedef __bf16 bf16x8 __attribute__((ext_vector_type(8)));
typedef __bf16 bf16x2 __attribute__((ext_vector_type(2)));
typedef short s16x4 __attribute__((ext_vector_type(4)));
typedef short s16x8 __attribute__((ext_vector_type(8)));
typedef float f32x4 __attribute__((ext_vector_type(4)));
typedef float f32x2 __attribute__((ext_vector_type(2)));

#define ASM_VMCNT0  asm volatile("s_waitcnt vmcnt(0)" ::: "memory")
#define ASM_BARRIER asm volatile("s_barrier" ::: "memory")

__device__ __forceinline__ unsigned short f2bf(float f) {
  union { float f; unsigned u; } v; v.f = f;
  unsigned r = v.u + 0x7fffu + ((v.u >> 16) & 1u);
  return (unsigned short)(r >> 16);
}
__device__ __forceinline__ unsigned pk2(float a, float b) {
  f32x2 v = {a, b};
  bf16x2 r = __builtin_convertvector(v, bf16x2);  // v_cvt_pk_bf16_f32
  union { bf16x2 h; unsigned u; } c; c.h = r;
  return c.u;
}
__device__ __forceinline__ void load_lds16(const void* g, void* l) {
  __builtin_amdgcn_global_load_lds((__attribute__((address_space(1))) void*)g,
                                   (__attribute__((address_space(3))) void*)l,
                                   16, 0, 0);
}

// ---------------------------------------------------------------------------
// fp32 -> bf16 conversion: x (4M) + wq/wk/wv/wo (1M each) into ws.
// ---------------------------------------------------------------------------
__global__ void cvt_all(const float* __restrict__ x, const float* __restrict__ wq,
                        const float* __restrict__ wk, const float* __restrict__ wv,
                        const float* __restrict__ wo, unsigned short* __restrict__ ws) {
  const int i = blockIdx.x * blockDim.x + threadIdx.x;
  const int off = i * 4;
  const float* src;
  unsigned short* dst;
  if (off < 4194304) {
    src = x + off;  dst = ws + off;
  } else {
    const int r = off - 4194304;
    const int w = r >> 20, o = r & 1048575;
    const float* tabs[4] = {wq, wk, wv, wo};
    src = tabs[w] + o;  dst = ws + 4194304 + (w << 20) + o;
  }
  const float4 v = *(const float4*)src;
  uint2 u;
  u.x = pk2(v.x, v.y);
  u.y = pk2(v.z, v.w);
  *(uint2*)dst = u;
}

// ---------------------------------------------------------------------------
// Fused QKV projection: C = x (4096x1024) @ W3^T (W3 = [wq;wk;wv], 3072x1024).
// 128x128 tiles, grid (24,32) = 768 blocks; 3 blocks/CU.
// V epilogue writes the key dim PERMUTED within each 64-block:
//   key = nb*16 + quad*4 + j  ->  g = quad*16 + (nb>>1)*8 + (nb&1)*4 + j
// so flash PV A-fragments (4 keys/lane, 2 nb per 16B) are b128-loadable.
// ---------------------------------------------------------------------------
__launch_bounds__(256, 3)
__global__ void gemm_qkv(const unsigned short* __restrict__ X,
                         const unsigned short* __restrict__ W3,
                         unsigned short* __restrict__ Qr,
                         unsigned short* __restrict__ Kr,
                         unsigned short* __restrict__ Vt,
                         const int* __restrict__ tp) {
  __shared__ __align__(16) char smem[32768];

  const int t = threadIdx.x;
  const int lane = t & 63, wave = t >> 6;
  const int quad = lane >> 4, l16 = lane & 15;
  const int m0 = blockIdx.y * 128, n0 = blockIdx.x * 128;
  const int wm = (wave >> 1) * 64, wn = (wave & 1) * 64;

  f32x4 acc[4][4];
#pragma unroll
  for (int i = 0; i < 4; i++)
#pragma unroll
    for (int j = 0; j < 4; j++) { acc[i][j][0]=0.f; acc[i][j][1]=0.f; acc[i][j][2]=0.f; acc[i][j][3]=0.f; }

  const int rr = t >> 2;
  const int cc = (t & 3) * 8;

#define QKV_STAGE(bufidx, k0_) do {                                               \
    char* a_ = smem + (bufidx) * 8192;                                            \
    char* b_ = smem + 16384 + (bufidx) * 8192;                                    \
    _Pragma("unroll")                                                             \
    for (int i_ = 0; i_ < 2; i_++) {                                              \
      load_lds16(X  + (uint64_t)(m0 + i_ * 64 + rr) * 1024 + (k0_) + cc,          \
                 a_ + i_ * 4096 + wave * 1024);                                   \
      load_lds16(W3 + (uint64_t)(n0 + i_ * 64 + rr) * 1024 + (k0_) + cc,          \
                 b_ + i_ * 4096 + wave * 1024);                                   \
    }                                                                             \
  } while (0)

  QKV_STAGE(0, 0);

  for (int k0 = 0; k0 < 1024; k0 += 32) {
    const int buf = (k0 >> 5) & 1;
    ASM_VMCNT0;
    ASM_BARRIER;
    if (k0 + 32 < 1024) QKV_STAGE(buf ^ 1, k0 + 32);
    char* As = smem + buf * 8192;
    char* Bs = smem + 16384 + buf * 8192;

    bf16x8 af[4], bfr[4];
#pragma unroll
    for (int i = 0; i < 4; i++) {
      af[i]  = *(const bf16x8*)(As + (wm + i * 16 + l16) * 64 + quad * 16);
      bfr[i] = *(const bf16x8*)(Bs + (wn + i * 16 + l16) * 64 + quad * 16);
    }
#pragma unroll
    for (int i = 0; i < 4; i++)
#pragma unroll
      for (int j = 0; j < 4; j++)
        acc[i][j] = __builtin_amdgcn_mfma_f32_16x16x32_bf16(af[i], bfr[j], acc[i][j], 0, 0, 0);
  }
#undef QKV_STAGE

  if (n0 < 2048) {
    unsigned short* dst = (n0 < 1024) ? Qr : Kr;
    float fr[4]; int dd[4], hh[4];
#pragma unroll
    for (int j = 0; j < 4; j++) {
      const int n = n0 + wn + j * 16 + l16;
      dd[j] = n & 63;
      hh[j] = (n & 1023) >> 6;
      fr[j] = __builtin_amdgcn_exp2f(-0.20762050594f * (float)(dd[j] & ~1)) * 0.15915494309f;
    }
    const float sgnodd = (l16 & 1) ? 1.f : -1.f;
#pragma unroll
    for (int i = 0; i < 4; i++) {
#pragma unroll
      for (int r = 0; r < 4; r++) {
        const int m = m0 + wm + i * 16 + quad * 4 + r;
        const int s = m & 2047, b = m >> 11;
        const float posf = (float)tp[m];
#pragma unroll
        for (int j = 0; j < 4; j++) {
          const float v = acc[i][j][r];
          const float p = __shfl_xor(v, 1);
          float rev = posf * fr[j];
          rev -= floorf(rev);
          float sn, cs;
          asm("v_sin_f32 %0, %1" : "=v"(sn) : "v"(rev));
          asm("v_cos_f32 %0, %1" : "=v"(cs) : "v"(rev));
          const float rv = fmaf(v, cs, p * sn * sgnodd);
          dst[((uint64_t)((b * NH + hh[j]) * SEQ + s)) * 64 + dd[j]] = f2bf(rv);
        }
      }
    }
  } else {
    // V -> Vt (b,h,d,s_permuted): 4 consecutive s (=j) share (quad_v, nb_v).
#pragma unroll
    for (int i = 0; i < 4; i++) {
      const int m = m0 + wm + i * 16 + quad * 4;
      const int s = m & 2047, b = m >> 11;
      const int sl = s & 63;
      const int qv = (sl >> 2) & 3, nv = sl >> 4;
      const int g = (s & ~63) + qv * 16 + (nv >> 1) * 8 + (nv & 1) * 4;
#pragma unroll
      for (int j = 0; j < 4; j++) {
        const int n = n0 - 2048 + wn + j * 16 + l16;
        const int h = n >> 6, d = n & 63;
        uint2 w;
        w.x = pk2(acc[i][j][0], acc[i][j][1]);
        w.y = pk2(acc[i][j][2], acc[i][j][3]);
        *(uint2*)(Vt + ((uint64_t)((b * NH + h) * 64 + d)) * SEQ + g) = w;
      }
    }
  }
}

// ---------------------------------------------------------------------------
// Output projection: C = At (4096x1024) @ wo^T, fp32 out. 128x128 tiles,
// grid (8,32) = 256 blocks (1/CU, uniform). 2x MFMA per staged byte vs 128x64.
// ---------------------------------------------------------------------------
__launch_bounds__(256, 2)
__global__ void gemm_ao(const unsigned short* __restrict__ A,
                        const unsigned short* __restrict__ B,
                        float* __restrict__ C) {
  __shared__ __align__(16) char smem[32768];

  const int t = threadIdx.x;
  const int lane = t & 63, wave = t >> 6;
  const int quad = lane >> 4, l16 = lane & 15;
  const int m0 = blockIdx.y * 128, n0 = blockIdx.x * 128;
  const int wm = (wave >> 1) * 64, wn = (wave & 1) * 64;

  f32x4 acc[4][4];
#pragma unroll
  for (int i = 0; i < 4; i++)
#pragma unroll
    for (int j = 0; j < 4; j++) { acc[i][j][0]=0.f; acc[i][j][1]=0.f; acc[i][j][2]=0.f; acc[i][j][3]=0.f; }

  const int rr = t >> 2;
  const int cc = (t & 3) * 8;

#define AO_STAGE(bufidx, k0_) do {                                               \
    char* a_ = smem + (bufidx) * 8192;                                            \
    char* b_ = smem + 16384 + (bufidx) * 8192;                                    \
    _Pragma("unroll")                                                             \
    for (int i_ = 0; i_ < 2; i_++) {                                              \
      load_lds16(A + (uint64_t)(m0 + i_ * 64 + rr) * 1024 + (k0_) + cc,           \
                 a_ + i_ * 4096 + wave * 1024);                                   \
      load_lds16(B + (uint64_t)(n0 + i_ * 64 + rr) * 1024 + (k0_) + cc,           \
                 b_ + i_ * 4096 + wave * 1024);                                   \
    }                                                                             \
  } while (0)

  AO_STAGE(0, 0);

  for (int k0 = 0; k0 < 1024; k0 += 32) {
    const int buf = (k0 >> 5) & 1;
    ASM_VMCNT0;
    ASM_BARRIER;
    if (k0 + 32 < 1024) AO_STAGE(buf ^ 1, k0 + 32);
    char* As = smem + buf * 8192;
    char* Bs = smem + 16384 + buf * 8192;

    bf16x8 af[4], bfr[4];
#pragma unroll
    for (int i = 0; i < 4; i++) {
      af[i]  = *(const bf16x8*)(As + (wm + i * 16 + l16) * 64 + quad * 16);
      bfr[i] = *(const bf16x8*)(Bs + (wn + i * 16 + l16) * 64 + quad * 16);
    }
#pragma unroll
    for (int i = 0; i < 4; i++)
#pragma unroll
      for (int j = 0; j < 4; j++)
        acc[i][j] = __builtin_amdgcn_mfma_f32_16x16x32_bf16(af[i], bfr[j], acc[i][j], 0, 0, 0);
  }
#undef AO_STAGE

#pragma unroll
  for (int i = 0; i < 4; i++)
#pragma unroll
    for (int j = 0; j < 4; j++)
#pragma unroll
      for (int r = 0; r < 4; r++) {
        const int m = m0 + wm + i * 16 + quad * 4 + r;
        const int n = n0 + wn + j * 16 + l16;
        C[(uint64_t)m * DM + n] = acc[i][j][r];
      }
}

// ---------------------------------------------------------------------------
// Flash attention: 256 blocks x 512 threads (8 waves). Block = one bh plane,
// Q-tile pair (128-row tiles a, 15-a) sequentially -> 34 uniform iterations.
// PV: P in registers (16x16x16 B-layout == S^T C-layout); V-frags read as
// b128 from the key-PERMUTED V layout (2 nb per 16B chunk, XOR-swizzled) --
// replaces r9's 16 b64 reads whose bank pattern caused 4.2e6 conflicts.
// ---------------------------------------------------------------------------
__launch_bounds__(512, 2)
__global__ void flash_attn(const unsigned short* __restrict__ Q,
                           const unsigned short* __restrict__ K,
                           const unsigned short* __restrict__ Vt,
                           unsigned short* __restrict__ Oa) {
  __shared__ __align__(16) char smem[32768];
  // K dbuf: 0 / 8192; V dbuf: 16384 / 24576

  const int t = threadIdx.x;
  const int lane = t & 63, wave = t >> 6;    // wave = 0..7
  const int quad = lane >> 4, l16 = lane & 15;
  const int lid = blockIdx.x;
  const int bh = lid & 31;
  const int a = lid >> 5;                    // 0..7 -> tile pair (a, 15-a)
  const uint64_t base = (uint64_t)bh * (SEQ * 64);
  const int qb0 = a * 128, qb1 = (15 - a) * 128;
  const int n0 = 2 * a + 2;                  // phase-0 iters (total 34)
  const int qg0 = qb0 + wave * 16 + l16;
  const int qg1 = qb1 + wave * 16 + l16;
  const int b = bh >> 4, h = bh & 15;

  // Q B-fragments for both phases (n=q=l16, k=d=kk*32+quad*8+j)
  bf16x8 qf0[2], qf1[2];
  {
    const unsigned short* qp = Q + base + (uint64_t)qg0 * 64 + quad * 8;
    qf0[0] = *(const bf16x8*)qp;  qf0[1] = *(const bf16x8*)(qp + 32);
    const unsigned short* qq = Q + base + (uint64_t)qg1 * 64 + quad * 8;
    qf1[0] = *(const bf16x8*)qq;  qf1[1] = *(const bf16x8*)(qq + 32);
  }

  f32x4 o[4];
#pragma unroll
  for (int i = 0; i < 4; i++) { o[i][0]=0.f; o[i][1]=0.f; o[i][2]=0.f; o[i][3]=0.f; }
  float lI = 0.f;

  // staging: 512 threads cover a 64-row x 128B tile in one call.
  // LDS chunk c at row r holds global 16B-chunk c ^ (r&7).
  const int srow = wave * 8 + (lane >> 3);
  const int sc = ((lane & 7) ^ ((lane >> 3) & 7)) * 8;   // shorts
  const int swz = (l16 & 7);

#define STAGE(bufidx, kb_) do {                                                   \
    load_lds16(K  + base + (uint64_t)((kb_) + srow) * 64 + sc,                    \
               smem + (bufidx) * 8192 + wave * 1024);                             \
    load_lds16(Vt + base + (uint64_t)srow * SEQ + (kb_) + sc,                     \
               smem + 16384 + (bufidx) * 8192 + wave * 1024);                     \
  } while (0)

  STAGE(0, 0);

  const float c1 = 0.18033688011f;  // log2(e)/8

  for (int it = 0; it < 34; it++) {
    const bool ph1 = it >= n0;
    const int kb = (ph1 ? it - n0 : it) * 64;
    const int buf = it & 1;
    ASM_VMCNT0;     // my stage(it) loads done (issued a full iteration ago)
    ASM_BARRIER;
    if (it + 1 < 34) {
      const int itn = it + 1;
      const int kbn = ((itn >= n0) ? itn - n0 : itn) * 64;
      STAGE(buf ^ 1, kbn);
    }
    char* ks = smem + buf * 8192;
    char* vs = smem + 16384 + buf * 8192;

    const bf16x8* qf = ph1 ? qf1 : qf0;
    const int qg = ph1 ? qg1 : qg0;
    const int qb = ph1 ? qb1 : qb0;
    int nbmax = ((qb + wave * 16 + 15 - kb) >> 4) + 1;
    nbmax = nbmax > 4 ? 4 : (nbmax < 0 ? 0 : nbmax);
    const bool diag = (kb + 63) > (qb + wave * 16);   // wave-uniform

    // S^T = K Q^T : key = kb + nb*16 + quad*4 + r, q = l16
    f32x4 sf[4];
    float ls = 0.f;
#pragma unroll
    for (int nb = 0; nb < 4; nb++) {
      if (nb < nbmax) {
        f32x4 s; s[0]=0.f; s[1]=0.f; s[2]=0.f; s[3]=0.f;
#pragma unroll
        for (int kk = 0; kk < 2; kk++) {
          bf16x8 kfr = *(const bf16x8*)(ks + (nb * 16 + l16) * 128 + (((kk * 4 + quad) ^ swz) * 16));
          s = __builtin_amdgcn_mfma_f32_16x16x32_bf16(kfr, qf[kk], s, 0, 0, 0);
        }
        if (diag) {
#pragma unroll
          for (int r = 0; r < 4; r++) {
            const int key = kb + nb * 16 + quad * 4 + r;
            const float p = (key <= qg) ? __builtin_amdgcn_exp2f(s[r] * c1) : 0.f;
            sf[nb][r] = p;  ls += p;
          }
        } else {
#pragma unroll
          for (int r = 0; r < 4; r++) {
            const float p = __builtin_amdgcn_exp2f(s[r] * c1);
            sf[nb][r] = p;  ls += p;
          }
        }
      }
    }
    lI += ls;   // lane-local partial (this quad's keys); reduced per phase

    // PV: P in regs; V-frag pair (nb=2np, 2np+1) in ONE b128 from permuted V.
#pragma unroll
    for (int np = 0; np < 2; np++) {
      if (2 * np < nbmax) {
        union { uint2 u; s16x4 h; } p0;
        p0.u.x = pk2(sf[2 * np][0], sf[2 * np][1]);
        p0.u.y = pk2(sf[2 * np][2], sf[2 * np][3]);
        const bool hi = (2 * np + 1 < nbmax);
        union { uint2 u; s16x4 h; } p1;
        if (hi) {
          p1.u.x = pk2(sf[2 * np + 1][0], sf[2 * np + 1][1]);
          p1.u.y = pk2(sf[2 * np + 1][2], sf[2 * np + 1][3]);
        }
#pragma unroll
        for (int db = 0; db < 4; db++) {
          s16x8 vv = *(const s16x8*)(vs + (db * 16 + l16) * 128 +
                                     (((quad * 2 + np) ^ swz) * 16));
          s16x4 vlo = __builtin_shufflevector(vv, vv, 0, 1, 2, 3);
          o[db] = __builtin_amdgcn_mfma_f32_16x16x16bf16_1k(vlo, p0.h, o[db], 0, 0, 0);
          if (hi) {
            s16x4 vhi = __builtin_shufflevector(vv, vv, 4, 5, 6, 7);
            o[db] = __builtin_amdgcn_mfma_f32_16x16x16bf16_1k(vhi, p1.h, o[db], 0, 0, 0);
          }
        }
      }
    }

    if (it == n0 - 1) {
      // end of phase 0: reduce l across quads, normalize, store, reset
      float lr = lI;
      lr += __shfl_xor(lr, 16);
      lr += __shfl_xor(lr, 32);
      const float invl = 1.0f / lr;
      unsigned short* orow = Oa + ((uint64_t)(b * SEQ + qg0)) * DM + h * 64 + quad * 4;
#pragma unroll
      for (int db = 0; db < 4; db++) {
        uint2 w;
        w.x = pk2(o[db][0] * invl, o[db][1] * invl);
        w.y = pk2(o[db][2] * invl, o[db][3] * invl);
        *(uint2*)(orow + db * 16) = w;
        o[db][0]=0.f; o[db][1]=0.f; o[db][2]=0.f; o[db][3]=0.f;
      }
      lI = 0.f;
    }
  }
#undef STAGE

  // phase-1 epilogue
  float lr = lI;
  lr += __shfl_xor(lr, 16);
  lr += __shfl_xor(lr, 32);
  const float invl = 1.0f / lr;
  unsigned short* orow = Oa + ((uint64_t)(b * SEQ + qg1)) * DM + h * 64 + quad * 4;
#pragma unroll
  for (int db = 0; db < 4; db++) {
    uint2 w;
    w.x = pk2(o[db][0] * invl, o[db][1] * invl);
    w.y = pk2(o[db][2] * invl, o[db][3] * invl);
    *(uint2*)(orow + db * 16) = w;
  }
}

extern "C" void kernel_launch(void* const* d_in, const int* in_sizes, int n_in,
                              void* d_out, int out_size, void* d_ws, size_t ws_size,
                              hipStream_t stream) {
  const float* x  = (const float*)d_in[0];
  const int* tp   = (const int*)d_in[1];
  const float* wq = (const float*)d_in[2];
  const float* wk = (const float*)d_in[3];
  const float* wv = (const float*)d_in[4];
  const float* wo = (const float*)d_in[5];
  float* out = (float*)d_out;

  unsigned short* ws = (unsigned short*)d_ws;
  unsigned short* xb  = ws;                   // (b,s,dm) bf16        8 MB
  unsigned short* w3b = ws + 4194304;         // [wq;wk;wv] 3072x1024 6 MB
  unsigned short* wob = ws + 7340032;         // 2 MB
  unsigned short* Qr  = ws + 8388608;         // (b,h,s,64)  8 MB
  unsigned short* Kr  = ws + 12582912;        // (b,h,s,64)  8 MB
  unsigned short* Vt  = ws + 16777216;        // (b,h,64,s-perm)  8 MB
  unsigned short* At  = ws + 20971520;        // (b,s,h*64)  8 MB

  cvt_all<<<8192, 256, 0, stream>>>(x, wq, wk, wv, wo, ws);
  gemm_qkv<<<dim3(24, 32), 256, 0, stream>>>(xb, w3b, Qr, Kr, Vt, tp);
  flash_attn<<<256, 512, 0, stream>>>(Qr, Kr, Vt, At);
  gemm_ao<<<dim3(8, 32), 256, 0, stream>>>(At, wob, out);
}